// Round 3
// baseline (111.586 us; speedup 1.0000x reference)
//
#include <hip/hip_runtime.h>
#include <math.h>

// DILATE / soft-DTW — round 15: r14 + __launch_bounds__(64, 1).
// r14 post-mortem: VGPR_Count=68 proved the double-buffered register windows
// (>=104 floats) were NEVER in registers — __launch_bounds__(64) made the
// compiler target 8 waves/SIMD (~64 VGPR budget) and sink the window loads
// into the compute loop, exposing ~120-cyc ds_read latency per step with a
// single wave per SIMD (wall 218 cyc/step vs ~60 issue + ~60 chain).
// The grid only ever co-locates 2 single-wave blocks per CU, so that
// occupancy target is unreachable and the register sacrifice bought nothing.
// r15: declare (64, 1) -> ~512 VGPR budget -> windows stay resident, the
// chunk-ahead prefetch (issued a full ~1200-cyc chunk early) hides all LDS
// latency. No other changes; per-cell op order identical -> absmax 0.0.
// Kept: band-serial single-wave blocks (no barriers), single float2 ring
// with producer==consumer wave, C2-domain carry (GLN2*C2==1 exact),
// subtract-form exp args (r5), DPP old-injection, unwritten-slot==(BIGC2,0).

#define NN     160
#define BC_TOT 512
#define B_SZ   64
#define C_SZ   8
#define BIGC2  1e12f              // border sentinel in C2 domain
#define SC2    12.01122405f       // sqrt(C2), C2 = 144.269504089
#define GLN2   0.0069314718056f   // gamma*ln2 == 1/C2
#define KPH    16
#define RSZ    328                // ring slots (reads up to 321)

__device__ __forceinline__ float fexp2(float x) {
#if __has_builtin(__builtin_amdgcn_exp2f)
    return __builtin_amdgcn_exp2f(x);
#else
    return exp2f(x);
#endif
}
__device__ __forceinline__ float flog2(float x) {
#if __has_builtin(__builtin_amdgcn_logf)
    return __builtin_amdgcn_logf(x);
#else
    return log2f(x);
#endif
}
__device__ __forceinline__ float frcp(float x) {
#if __has_builtin(__builtin_amdgcn_rcpf)
    return __builtin_amdgcn_rcpf(x);
#else
    return 1.0f / x;
#endif
}
// lane i <- lane i-1; lane 0 <- old (bound_ctrl=false). Standard scan idiom.
__device__ __forceinline__ float dpp_up1_inj(float old, float x) {
    int oi = __builtin_bit_cast(int, old);
    int xi = __builtin_bit_cast(int, x);
    return __builtin_bit_cast(float,
        __builtin_amdgcn_update_dpp(oi, xi, 0x138, 0xF, 0xF, false)); // wave_shr1
}
// LDS-only barrier (no vmcnt drain). 0xC07F = vmcnt(63) expcnt(7) lgkmcnt(0).
__device__ __forceinline__ void barrier_lds() {
    __asm__ __volatile__("" ::: "memory");
    __builtin_amdgcn_s_waitcnt(0xC07F);
    __builtin_amdgcn_s_barrier();
    __asm__ __volatile__("" ::: "memory");
}

// Load register window for chunk c_: ring slots [dlo-2, dlo+15] + P window.
#define LOAD_WIN(c_, rgx_, rgd_, pvv_) do {                                   \
    const int dlo_ = 2 + (c_) * KPH;                                          \
    if (w > 0) {                                                              \
        const float4* q_ = (const float4*)&bRG[dlo_ - 2];                     \
        _Pragma("unroll")                                                     \
        for (int x_ = 0; x_ < 9; ++x_) {                                      \
            const float4 v4_ = q_[x_];                                        \
            rgx_[2 * x_]     = v4_.x; rgd_[2 * x_]     = v4_.y;               \
            rgx_[2 * x_ + 1] = v4_.z; rgd_[2 * x_ + 1] = v4_.w;               \
        }                                                                     \
    } else {                                                                  \
        _Pragma("unroll")                                                     \
        for (int x_ = 0; x_ < 18; ++x_) { rgx_[x_] = BIGC2; rgd_[x_] = 0.0f; }\
        if ((c_) == 0) rgx_[0] = 0.0f;   /* R[0][0] = 0 seed at d=2 */        \
    }                                                                         \
    const int A_  = 192 - (64 * w + lane) + KPH * (c_);                       \
    const int sA_ = A_ & 3;                                                   \
    const float4* pq_ = (const float4*)&Pp[sA_][A_ - sA_];                    \
    _Pragma("unroll")                                                         \
    for (int x_ = 0; x_ < 4; ++x_) {                                          \
        const float4 p4_ = pq_[x_];                                           \
        pvv_[4 * x_]     = p4_.x; pvv_[4 * x_ + 1] = p4_.y;                   \
        pvv_[4 * x_ + 2] = p4_.z; pvv_[4 * x_ + 3] = p4_.w;                   \
    }                                                                         \
} while (0)

// 16 DP steps of chunk c_ using window regs. Op order identical to r12.
#define COMP_CHUNK(c_, rgx_, rgd_, pvv_) do {                                 \
    const int dlo_ = 2 + (c_) * KPH;                                          \
    if ((c_) == cLo) {   /* one-time boundary injection (first chunk) */      \
        u1 = isL0 ? rgx_[1] : BIGC2;  u2 = isL0 ? rgx_[0] : BIGC2;            \
        v1 = isL0 ? rgd_[1] : 0.0f;   v2 = isL0 ? rgd_[0] : 0.0f;             \
    }                                                                         \
    float djf_ = (float)(dlo_ - ti2);    /* j - i at u=0 */                   \
    _Pragma("unroll")                                                         \
    for (int u_ = 0; u_ < KPH; ++u_) {                                        \
        const int d_ = dlo_ + u_;                                             \
        const float mn = fminf(u2, fminf(u1, r1));                            \
        const float ed = fexp2(mn - u2);   /* SUBTRACT form (r5 rule) */      \
        const float ev = fexp2(mn - u1);                                      \
        const float eh = fexp2(mn - r1);                                      \
        const float ss = ed + ev + eh;     /* >= 1 */                         \
        const float rs = frcp(ss);                                            \
        const float dt = trS - pvv_[u_];                                      \
        const float rC = __builtin_fmaf(dt, dt, mn) - flog2(ss);              \
        const float nm = __builtin_fmaf(ed, v2,                               \
                         __builtin_fmaf(ev, v1, eh * s1));                    \
        const float rd = __builtin_fmaf(nm, rs, djf_ * djf_);                 \
        if (pub) { float2 pb; pb.x = rC; pb.y = rd; bRG[d_] = pb; }           \
        if (d_ == 2 * NN) {                                                   \
            if (w == 2 && lane == NN - 1 - 128) {  /* cell (160,160) */       \
                sdtw[k] = rC * GLN2;                                          \
                wlt[k]  = rd * (1.0f / (NN * NN));                            \
            }                                                                 \
        }                                                                     \
        u2 = u1; u1 = dpp_up1_inj(rgx_[u_ + 2], rC);  /* lane0 <- slot d */   \
        v2 = v1; v1 = dpp_up1_inj(rgd_[u_ + 2], rd);                          \
        r1 = rC; s1 = rd;                                                     \
        djf_ += 1.0f;                                                         \
    }                                                                         \
} while (0)

__global__ __launch_bounds__(64, 1)   // 1 wave/EU min -> full VGPR budget
void dtw_fwd_kernel(const float* __restrict__ input,
                    const float* __restrict__ target,
                    float* __restrict__ sdtw,    // BC_TOT: R[N,N]
                    float* __restrict__ wlt)     // BC_TOT: Rdot[N,N]/N^2
{
    const int k    = blockIdx.x;
    const int lane = threadIdx.x;                // 0..63, one wave

    __shared__ __align__(16) float  Pp[4][520];  // replica s: Pp[s][y]=V(y+s)*SC2
    __shared__ __align__(16) float2 bRG[RSZ];    // ring: (rC2, rdot) @ slot=diag

    const float* tg = target + (size_t)k * NN;
    const float* pg = input  + (size_t)k * NN;
    // V(z) = P[z-192]*SC2 for z in [192,352), else 0
    for (int x = lane; x < 520; x += 64) {
        #pragma unroll
        for (int s = 0; s < 4; ++s) {
            const int v = x + s - 192;
            Pp[s][x] = ((unsigned)v < (unsigned)NN) ? pg[v] * SC2 : 0.0f;
        }
    }
    for (int x = lane; x < RSZ; x += 64) {
        float2 z; z.x = BIGC2; z.y = 0.0f;       // unwritten slot == true border
        bRG[x] = z;
    }
    const float tr0 = tg[lane] * SC2;            // rows 1..64
    const float tr1 = tg[64 + lane] * SC2;       // rows 65..128
    const float tr2 = (lane < NN - 128) ? tg[128 + lane] * SC2 : 0.0f; // 129..160
    barrier_lds();

    const bool isL0 = (lane == 0);

    for (int w = 0; w < 3; ++w) {                // SERIAL bands, same wave
        // cross-band LDS ordering fence (compiler-level; HW DS is in-order)
        __asm__ __volatile__("" ::: "memory");
        const int  cLo = 4 * w;                  // chunks [4w, min(19,4w+13)]
        const int  cHi = (4 * w + 13 < 19) ? 4 * w + 13 : 19;
        const bool pub = (lane == 63) && (w < 2);
        const float trS = (w == 0) ? tr0 : (w == 1) ? tr1 : tr2;
        const int  ti2 = 2 * (64 * w + lane + 1);   // 2*i

        // rolling state (C2 domain); borders reset per band
        float r1 = BIGC2, u1 = BIGC2, u2 = BIGC2;
        float s1 = 0.0f,  v1 = 0.0f,  v2 = 0.0f;

        float rgxA[18], rgdA[18], pvvA[16];
        float rgxB[18], rgdB[18], pvvB[16];

        LOAD_WIN(cLo, rgxA, rgdA, pvvA);
        for (int c = cLo; c <= cHi; c += 2) {    // even chunk counts: 14/14/12
            LOAD_WIN(c + 1, rgxB, rgdB, pvvB);   // prefetch under compute
            COMP_CHUNK(c, rgxA, rgdA, pvvA);
            if (c + 2 <= cHi) LOAD_WIN(c + 2, rgxA, rgdA, pvvA);
            COMP_CHUNK(c + 1, rgxB, rgdB, pvvB);
        }
    }
}

// final reduction: per-batch means + scalar loss. One wave (64 threads = B).
__global__ __launch_bounds__(64)
void finalize_kernel(const float* __restrict__ sdtw,
                     const float* __restrict__ wlt,
                     float* __restrict__ out)
{
    const int b = threadIdx.x;   // 0..63
    float ls = 0.0f, lt = 0.0f;
    #pragma unroll
    for (int c = 0; c < C_SZ; ++c) {
        ls += sdtw[b * C_SZ + c];
        lt += wlt[b * C_SZ + c];
    }
    ls *= (1.0f / C_SZ);
    lt *= (1.0f / C_SZ);
    out[1 + b]        = ls;
    out[1 + B_SZ + b] = lt;
    float v = 0.5f * ls + 0.5f * lt;
    #pragma unroll
    for (int o = 32; o > 0; o >>= 1) v += __shfl_down(v, o);
    if (b == 0) out[0] = v * (1.0f / B_SZ);
}

extern "C" void kernel_launch(void* const* d_in, const int* in_sizes, int n_in,
                              void* d_out, int out_size, void* d_ws, size_t ws_size,
                              hipStream_t stream) {
    const float* input  = (const float*)d_in[0];
    const float* target = (const float*)d_in[1];
    float* out = (float*)d_out;   // 129 floats

    float* sdtw = (float*)d_ws;                 // 512 floats
    float* wlt  = sdtw + BC_TOT;                // 512 floats

    dtw_fwd_kernel<<<BC_TOT, 64, 0, stream>>>(input, target, sdtw, wlt);
    finalize_kernel<<<1, 64, 0, stream>>>(sdtw, wlt, out);
}

// Round 4
// 110.252 us; speedup vs baseline: 1.0121x; 1.0121x over previous
//
#include <hip/hip_runtime.h>
#include <math.h>

// DILATE / soft-DTW — round 16: r15 + sched_barrier(0) to PIN the prefetch.
// r15 post-mortem: VGPR stayed 68, dur identical — __launch_bounds__(64,1)
// only raised the register BUDGET; the machine scheduler still minimizes
// pressure and sank all 13 window ds_read_b128s into the compute loop next
// to their uses. The double-buffer existed only in C source.
// r16: __builtin_amdgcn_sched_barrier(0) immediately after every LOAD_WIN.
// No instruction may cross the fence in either direction, so:
//   - the 13 window loads must ISSUE before the fence (early, chunk-ahead),
//   - the ~1000-cyc compute of the current chunk cannot hoist above it,
//   - loaded values are forced live across the chunk (ds_read is not
//     rematerializable -> allocator must keep them in VGPRs; budget is 512).
// Compiler still auto-inserts the lgkmcnt wait before first use in the NEXT
// chunk, by which point the loads completed under the current chunk's math.
// Expected: VGPR >= 160 (verification gate), wall/step ~300 -> ~70 cyc.
// Ring hazard analysis unchanged from r14: prefetch(c+1) overlaps chunk c's
// writes only at window slots rgx[0..1], which are dead except at a band's
// first chunk (loaded at band start, no overlap there).
// Kept: band-serial single-wave blocks (no barriers), single float2 ring,
// C2-domain carry (GLN2*C2==1 exact), subtract-form exp args (r5), DPP
// old-injection, unwritten-slot==(BIGC2,0) borders. Numerics identical
// to r12 -> absmax 0.0.

#define NN     160
#define BC_TOT 512
#define B_SZ   64
#define C_SZ   8
#define BIGC2  1e12f              // border sentinel in C2 domain
#define SC2    12.01122405f       // sqrt(C2), C2 = 144.269504089
#define GLN2   0.0069314718056f   // gamma*ln2 == 1/C2
#define KPH    16
#define RSZ    328                // ring slots (reads up to 321)

__device__ __forceinline__ float fexp2(float x) {
#if __has_builtin(__builtin_amdgcn_exp2f)
    return __builtin_amdgcn_exp2f(x);
#else
    return exp2f(x);
#endif
}
__device__ __forceinline__ float flog2(float x) {
#if __has_builtin(__builtin_amdgcn_logf)
    return __builtin_amdgcn_logf(x);
#else
    return log2f(x);
#endif
}
__device__ __forceinline__ float frcp(float x) {
#if __has_builtin(__builtin_amdgcn_rcpf)
    return __builtin_amdgcn_rcpf(x);
#else
    return 1.0f / x;
#endif
}
// lane i <- lane i-1; lane 0 <- old (bound_ctrl=false). Standard scan idiom.
__device__ __forceinline__ float dpp_up1_inj(float old, float x) {
    int oi = __builtin_bit_cast(int, old);
    int xi = __builtin_bit_cast(int, x);
    return __builtin_bit_cast(float,
        __builtin_amdgcn_update_dpp(oi, xi, 0x138, 0xF, 0xF, false)); // wave_shr1
}
// LDS-only barrier (no vmcnt drain). 0xC07F = vmcnt(63) expcnt(7) lgkmcnt(0).
__device__ __forceinline__ void barrier_lds() {
    __asm__ __volatile__("" ::: "memory");
    __builtin_amdgcn_s_waitcnt(0xC07F);
    __builtin_amdgcn_s_barrier();
    __asm__ __volatile__("" ::: "memory");
}

// Scheduling fence: nothing moves across. Pins prefetch issue-point.
#define PIN() __builtin_amdgcn_sched_barrier(0)

// Load register window for chunk c_: ring slots [dlo-2, dlo+15] + P window.
#define LOAD_WIN(c_, rgx_, rgd_, pvv_) do {                                   \
    const int dlo_ = 2 + (c_) * KPH;                                          \
    if (w > 0) {                                                              \
        const float4* q_ = (const float4*)&bRG[dlo_ - 2];                     \
        _Pragma("unroll")                                                     \
        for (int x_ = 0; x_ < 9; ++x_) {                                      \
            const float4 v4_ = q_[x_];                                        \
            rgx_[2 * x_]     = v4_.x; rgd_[2 * x_]     = v4_.y;               \
            rgx_[2 * x_ + 1] = v4_.z; rgd_[2 * x_ + 1] = v4_.w;               \
        }                                                                     \
    } else {                                                                  \
        _Pragma("unroll")                                                     \
        for (int x_ = 0; x_ < 18; ++x_) { rgx_[x_] = BIGC2; rgd_[x_] = 0.0f; }\
        if ((c_) == 0) rgx_[0] = 0.0f;   /* R[0][0] = 0 seed at d=2 */        \
    }                                                                         \
    const int A_  = 192 - (64 * w + lane) + KPH * (c_);                       \
    const int sA_ = A_ & 3;                                                   \
    const float4* pq_ = (const float4*)&Pp[sA_][A_ - sA_];                    \
    _Pragma("unroll")                                                         \
    for (int x_ = 0; x_ < 4; ++x_) {                                          \
        const float4 p4_ = pq_[x_];                                           \
        pvv_[4 * x_]     = p4_.x; pvv_[4 * x_ + 1] = p4_.y;                   \
        pvv_[4 * x_ + 2] = p4_.z; pvv_[4 * x_ + 3] = p4_.w;                   \
    }                                                                         \
} while (0)

// 16 DP steps of chunk c_ using window regs. Op order identical to r12.
#define COMP_CHUNK(c_, rgx_, rgd_, pvv_) do {                                 \
    const int dlo_ = 2 + (c_) * KPH;                                          \
    if ((c_) == cLo) {   /* one-time boundary injection (first chunk) */      \
        u1 = isL0 ? rgx_[1] : BIGC2;  u2 = isL0 ? rgx_[0] : BIGC2;            \
        v1 = isL0 ? rgd_[1] : 0.0f;   v2 = isL0 ? rgd_[0] : 0.0f;             \
    }                                                                         \
    float djf_ = (float)(dlo_ - ti2);    /* j - i at u=0 */                   \
    _Pragma("unroll")                                                         \
    for (int u_ = 0; u_ < KPH; ++u_) {                                        \
        const int d_ = dlo_ + u_;                                             \
        const float mn = fminf(u2, fminf(u1, r1));                            \
        const float ed = fexp2(mn - u2);   /* SUBTRACT form (r5 rule) */      \
        const float ev = fexp2(mn - u1);                                      \
        const float eh = fexp2(mn - r1);                                      \
        const float ss = ed + ev + eh;     /* >= 1 */                         \
        const float rs = frcp(ss);                                            \
        const float dt = trS - pvv_[u_];                                      \
        const float rC = __builtin_fmaf(dt, dt, mn) - flog2(ss);              \
        const float nm = __builtin_fmaf(ed, v2,                               \
                         __builtin_fmaf(ev, v1, eh * s1));                    \
        const float rd = __builtin_fmaf(nm, rs, djf_ * djf_);                 \
        if (pub) { float2 pb; pb.x = rC; pb.y = rd; bRG[d_] = pb; }           \
        if (d_ == 2 * NN) {                                                   \
            if (w == 2 && lane == NN - 1 - 128) {  /* cell (160,160) */       \
                sdtw[k] = rC * GLN2;                                          \
                wlt[k]  = rd * (1.0f / (NN * NN));                            \
            }                                                                 \
        }                                                                     \
        u2 = u1; u1 = dpp_up1_inj(rgx_[u_ + 2], rC);  /* lane0 <- slot d */   \
        v2 = v1; v1 = dpp_up1_inj(rgd_[u_ + 2], rd);                          \
        r1 = rC; s1 = rd;                                                     \
        djf_ += 1.0f;                                                         \
    }                                                                         \
} while (0)

__global__ __launch_bounds__(64, 1)   // 1 wave/EU min -> full VGPR budget
void dtw_fwd_kernel(const float* __restrict__ input,
                    const float* __restrict__ target,
                    float* __restrict__ sdtw,    // BC_TOT: R[N,N]
                    float* __restrict__ wlt)     // BC_TOT: Rdot[N,N]/N^2
{
    const int k    = blockIdx.x;
    const int lane = threadIdx.x;                // 0..63, one wave

    __shared__ __align__(16) float  Pp[4][520];  // replica s: Pp[s][y]=V(y+s)*SC2
    __shared__ __align__(16) float2 bRG[RSZ];    // ring: (rC2, rdot) @ slot=diag

    const float* tg = target + (size_t)k * NN;
    const float* pg = input  + (size_t)k * NN;
    // V(z) = P[z-192]*SC2 for z in [192,352), else 0
    for (int x = lane; x < 520; x += 64) {
        #pragma unroll
        for (int s = 0; s < 4; ++s) {
            const int v = x + s - 192;
            Pp[s][x] = ((unsigned)v < (unsigned)NN) ? pg[v] * SC2 : 0.0f;
        }
    }
    for (int x = lane; x < RSZ; x += 64) {
        float2 z; z.x = BIGC2; z.y = 0.0f;       // unwritten slot == true border
        bRG[x] = z;
    }
    const float tr0 = tg[lane] * SC2;            // rows 1..64
    const float tr1 = tg[64 + lane] * SC2;       // rows 65..128
    const float tr2 = (lane < NN - 128) ? tg[128 + lane] * SC2 : 0.0f; // 129..160
    barrier_lds();

    const bool isL0 = (lane == 0);

    for (int w = 0; w < 3; ++w) {                // SERIAL bands, same wave
        // cross-band LDS ordering fence (compiler-level; HW DS is in-order)
        __asm__ __volatile__("" ::: "memory");
        const int  cLo = 4 * w;                  // chunks [4w, min(19,4w+13)]
        const int  cHi = (4 * w + 13 < 19) ? 4 * w + 13 : 19;
        const bool pub = (lane == 63) && (w < 2);
        const float trS = (w == 0) ? tr0 : (w == 1) ? tr1 : tr2;
        const int  ti2 = 2 * (64 * w + lane + 1);   // 2*i

        // rolling state (C2 domain); borders reset per band
        float r1 = BIGC2, u1 = BIGC2, u2 = BIGC2;
        float s1 = 0.0f,  v1 = 0.0f,  v2 = 0.0f;

        float rgxA[18], rgdA[18], pvvA[16];
        float rgxB[18], rgdB[18], pvvB[16];

        LOAD_WIN(cLo, rgxA, rgdA, pvvA);
        PIN();                                   // pin band-start window
        for (int c = cLo; c <= cHi; c += 2) {    // even chunk counts: 14/14/12
            LOAD_WIN(c + 1, rgxB, rgdB, pvvB);   // prefetch under compute
            PIN();                               // loads must issue HERE
            COMP_CHUNK(c, rgxA, rgdA, pvvA);
            if (c + 2 <= cHi) {
                LOAD_WIN(c + 2, rgxA, rgdA, pvvA);
                PIN();                           // loads must issue HERE
            }
            COMP_CHUNK(c + 1, rgxB, rgdB, pvvB);
        }
    }
}

// final reduction: per-batch means + scalar loss. One wave (64 threads = B).
__global__ __launch_bounds__(64)
void finalize_kernel(const float* __restrict__ sdtw,
                     const float* __restrict__ wlt,
                     float* __restrict__ out)
{
    const int b = threadIdx.x;   // 0..63
    float ls = 0.0f, lt = 0.0f;
    #pragma unroll
    for (int c = 0; c < C_SZ; ++c) {
        ls += sdtw[b * C_SZ + c];
        lt += wlt[b * C_SZ + c];
    }
    ls *= (1.0f / C_SZ);
    lt *= (1.0f / C_SZ);
    out[1 + b]        = ls;
    out[1 + B_SZ + b] = lt;
    float v = 0.5f * ls + 0.5f * lt;
    #pragma unroll
    for (int o = 32; o > 0; o >>= 1) v += __shfl_down(v, o);
    if (b == 0) out[0] = v * (1.0f / B_SZ);
}

extern "C" void kernel_launch(void* const* d_in, const int* in_sizes, int n_in,
                              void* d_out, int out_size, void* d_ws, size_t ws_size,
                              hipStream_t stream) {
    const float* input  = (const float*)d_in[0];
    const float* target = (const float*)d_in[1];
    float* out = (float*)d_out;   // 129 floats

    float* sdtw = (float*)d_ws;                 // 512 floats
    float* wlt  = sdtw + BC_TOT;                // 512 floats

    dtw_fwd_kernel<<<BC_TOT, 64, 0, stream>>>(input, target, sdtw, wlt);
    finalize_kernel<<<1, 64, 0, stream>>>(sdtw, wlt, out);
}

// Round 5
// 101.394 us; speedup vs baseline: 1.1005x; 1.0874x over previous
//
#include <hip/hip_runtime.h>
#include <math.h>

// DILATE / soft-DTW — round 17: SYSTOLIC ROW-BLOCKED sweep (no ring, no
// barriers, no LDS windows). r14-r16 post-mortem: three attempts to keep a
// 104-float LDS window register-resident all failed (VGPR stuck at 68; the
// scheduler sinks cross-BB loads regardless of launch_bounds/sched_barrier).
// r17 removes the window entirely by changing the decomposition:
//   lane l owns rows 3l+1..3l+3 (54 lanes cover N=160).
//   cell (i,j) computed at wall-step t = i+j-2  (j = t - 3l - s + 1).
//   s>=1: all 3 predecessors are IN-LANE register values from steps t-1/t-2.
//   s==0: up/diag come from lane l-1's 3rd row via 1-lane DPP (produced one
//         step earlier) — the same dpp_up1_inj idiom, lane 0 injects borders.
// Per step: 3 independent softmin cell-chains per lane (in-wave ILP hides
// the ~40-cyc chain), 1 scalar LDS read (P value, prefetched 4 ahead),
// 2 DPP. 319 steps total. No s_barrier anywhere in the sweep.
// Border correctness without masking: P array zero-padded so pv==0 exactly
// while a lane is inactive (idx<192 <=> j<1); junk "borders" stay ~1e12
// (per-step drift <= log2(3)), so weights exp2(mn - 1e12) == 0 exactly and
// min() never selects them vs real values (<= ~3e6). Every real cell has a
// real predecessor; only R[0][0]=0 needs exact injection (lane0 b0 init).
// Real-cell op order identical to r12 -> absmax 0.0.
// Kept: C2-domain carry (GLN2*C2==1 exact), subtract-form exp args (r5),
// forward-mode AD, 512 x 64 launch (2 waves/CU).

#define NN     160
#define BC_TOT 512
#define B_SZ   64
#define C_SZ   8
#define BIGC2  1e12f              // border sentinel in C2 domain
#define SC2    12.01122405f       // sqrt(C2), C2 = 144.269504089
#define GLN2   0.0069314718056f   // gamma*ln2 == 1/C2

__device__ __forceinline__ float fexp2(float x) {
#if __has_builtin(__builtin_amdgcn_exp2f)
    return __builtin_amdgcn_exp2f(x);
#else
    return exp2f(x);
#endif
}
__device__ __forceinline__ float flog2(float x) {
#if __has_builtin(__builtin_amdgcn_logf)
    return __builtin_amdgcn_logf(x);
#else
    return log2f(x);
#endif
}
__device__ __forceinline__ float frcp(float x) {
#if __has_builtin(__builtin_amdgcn_rcpf)
    return __builtin_amdgcn_rcpf(x);
#else
    return 1.0f / x;
#endif
}
// lane i <- lane i-1; lane 0 <- old (bound_ctrl=false). Standard scan idiom.
__device__ __forceinline__ float dpp_up1_inj(float old, float x) {
    int oi = __builtin_bit_cast(int, old);
    int xi = __builtin_bit_cast(int, x);
    return __builtin_bit_cast(float,
        __builtin_amdgcn_update_dpp(oi, xi, 0x138, 0xF, 0xF, false)); // wave_shr1
}

// One wall-step: 3 cells (sub-rows 0..2) from OLD state, then rotate.
// PV0 = P value for s=0 this step (pva/pvb carry s=1/s=2 via rotation).
#define STEP(PV0) do {                                                        \
    /* ---- s = 0 : row 3l+1 (needs lane l-1 via a0/b0) ---- */               \
    const float mn0 = fminf(b0, fminf(a0, r0));                               \
    const float ed0 = fexp2(mn0 - b0);   /* SUBTRACT form (r5 rule) */        \
    const float ev0 = fexp2(mn0 - a0);                                        \
    const float eh0 = fexp2(mn0 - r0);                                        \
    const float ss0 = ed0 + ev0 + eh0;                                        \
    const float rs0 = frcp(ss0);                                              \
    const float dt0 = trS0 - (PV0);                                           \
    const float n0  = __builtin_fmaf(dt0, dt0, mn0) - flog2(ss0);             \
    const float nm0 = __builtin_fmaf(ed0, bd0,                                \
                      __builtin_fmaf(ev0, ad0, eh0 * g0));                    \
    const float om0 = dj0 * dj0;                                              \
    const float nd0 = __builtin_fmaf(nm0, rs0, om0);                          \
    /* ---- s = 1 : row 3l+2 (all in-lane) ---- */                            \
    const float mn1 = fminf(b1, fminf(a1, r1));                               \
    const float ed1 = fexp2(mn1 - b1);                                        \
    const float ev1 = fexp2(mn1 - a1);                                        \
    const float eh1 = fexp2(mn1 - r1);                                        \
    const float ss1 = ed1 + ev1 + eh1;                                        \
    const float rs1 = frcp(ss1);                                              \
    const float dt1 = trS1 - pva;                                             \
    const float n1  = __builtin_fmaf(dt1, dt1, mn1) - flog2(ss1);             \
    const float nm1 = __builtin_fmaf(ed1, bd1,                                \
                      __builtin_fmaf(ev1, ad1, eh1 * g1));                    \
    const float dj1 = dj0 - 2.0f;                                             \
    const float nd1 = __builtin_fmaf(nm1, rs1, dj1 * dj1);                    \
    /* ---- s = 2 : row 3l+3 (all in-lane) ---- */                            \
    const float mn2 = fminf(b2, fminf(a2, r2));                               \
    const float ed2 = fexp2(mn2 - b2);                                        \
    const float ev2 = fexp2(mn2 - a2);                                        \
    const float eh2 = fexp2(mn2 - r2);                                        \
    const float ss2 = ed2 + ev2 + eh2;                                        \
    const float rs2 = frcp(ss2);                                              \
    const float dt2 = trS2 - pvb;                                             \
    const float n2  = __builtin_fmaf(dt2, dt2, mn2) - flog2(ss2);             \
    const float nm2 = __builtin_fmaf(ed2, bd2,                                \
                      __builtin_fmaf(ev2, ad2, eh2 * g2));                    \
    const float dj2 = dj0 - 4.0f;                                             \
    const float nd2 = __builtin_fmaf(nm2, rs2, dj2 * dj2);                    \
    /* ---- rotations (read OLD values, then overwrite) ---- */               \
    b2 = a2;  bd2 = ad2;  a2 = n1;  ad2 = nd1;                                \
    b1 = a1;  bd1 = ad1;  a1 = n0;  ad1 = nd0;                                \
    b0 = a0;  bd0 = ad0;                                                      \
    a0  = dpp_up1_inj(BIGC2, n2);   /* lane0 <- R[0][j] = border */           \
    ad0 = dpp_up1_inj(0.0f,  nd2);  /* lane0 <- Rdot[0][j] = 0    */          \
    r0 = n0; r1 = n1; r2 = n2;                                                \
    g0 = nd0; g1 = nd1; g2 = nd2;                                             \
    pvb = pva; pva = (PV0);                                                   \
    dj0 += 1.0f;                                                              \
} while (0)

__global__ __launch_bounds__(64, 1)
void dtw_fwd_kernel(const float* __restrict__ input,
                    const float* __restrict__ target,
                    float* __restrict__ sdtw,    // BC_TOT: R[N,N]
                    float* __restrict__ wlt)     // BC_TOT: Rdot[N,N]/N^2
{
    const int k    = blockIdx.x;
    const int lane = threadIdx.x;                // 0..63, one wave

    __shared__ __align__(16) float Pp[512];      // Pp[x] = pg[x-192]*SC2, pad 0

    const float* tg = target + (size_t)k * NN;
    const float* pg = input  + (size_t)k * NN;
    #pragma unroll
    for (int x0 = 0; x0 < 512; x0 += 64) {
        const int x = x0 + lane;
        const int v = x - 192;
        Pp[x] = ((unsigned)v < (unsigned)NN) ? pg[v] * SC2 : 0.0f;
    }
    // T values for the lane's 3 rows (i = 3l+1..3l+3 -> T[3l+s])
    const int r3 = 3 * lane;
    const float trS0 = (r3 + 0 < NN) ? tg[r3 + 0] * SC2 : 0.0f;
    const float trS1 = (r3 + 1 < NN) ? tg[r3 + 1] * SC2 : 0.0f;
    const float trS2 = (r3 + 2 < NN) ? tg[r3 + 2] * SC2 : 0.0f;
    // single wave: LDS write->read needs only a wait, no barrier
    __asm__ __volatile__("" ::: "memory");
    __builtin_amdgcn_s_waitcnt(0xC07F);          // lgkmcnt(0)
    __asm__ __volatile__("" ::: "memory");

    // rolling state (C2 domain): r*/g* = left (R, Rdot); a*/ad* = up;
    // b*/bd* = diag. Inits are borders; lane0 b0 = R[0][0] = 0 exact.
    float r0 = BIGC2, r1 = BIGC2, r2 = BIGC2;
    float g0 = 0.0f,  g1 = 0.0f,  g2 = 0.0f;
    float a0 = BIGC2, a1 = BIGC2, a2 = BIGC2;
    float ad0 = 0.0f, ad1 = 0.0f, ad2 = 0.0f;
    float b0 = (lane == 0) ? 0.0f : BIGC2;
    float b1 = BIGC2, b2 = BIGC2;
    float bd0 = 0.0f, bd1 = 0.0f, bd2 = 0.0f;

    float pva = 0.0f, pvb = 0.0f;                // pv of steps t-1, t-2
    float dj0 = (float)(-6 * lane);              // (j - i) for s=0 at t=0

    const int pb = 192 - r3;                     // pidx(t) = pb + t
    // P prefetch: 4-step register buffer, software-pipelined one block ahead.
    float pf0 = Pp[pb + 0], pf1 = Pp[pb + 1], pf2 = Pp[pb + 2], pf3 = Pp[pb + 3];

    // 79 blocks of 4 steps = 316, + 3 epilogue = 319 steps (t = 0..318)
    for (int tb = 0; tb < 79; ++tb) {
        const int tn = 4 * tb + 4;
        const float q0 = Pp[pb + tn + 0];
        const float q1 = Pp[pb + tn + 1];
        const float q2 = Pp[pb + tn + 2];
        const float q3 = Pp[pb + tn + 3];
        STEP(pf0); STEP(pf1); STEP(pf2); STEP(pf3);
        pf0 = q0; pf1 = q1; pf2 = q2; pf3 = q3;
    }
    STEP(pf0); STEP(pf1); STEP(pf2);             // t = 316, 317, 318

    // lane 53, s=0 is row 160; its last computed cell (t=318) is (160,160),
    // still in r0/g0 after the final rotation.
    if (lane == 53) {
        sdtw[k] = r0 * GLN2;                     // back to normal domain
        wlt[k]  = g0 * (1.0f / (NN * NN));
    }
}

// final reduction: per-batch means + scalar loss. One wave (64 threads = B).
__global__ __launch_bounds__(64)
void finalize_kernel(const float* __restrict__ sdtw,
                     const float* __restrict__ wlt,
                     float* __restrict__ out)
{
    const int b = threadIdx.x;   // 0..63
    float ls = 0.0f, lt = 0.0f;
    #pragma unroll
    for (int c = 0; c < C_SZ; ++c) {
        ls += sdtw[b * C_SZ + c];
        lt += wlt[b * C_SZ + c];
    }
    ls *= (1.0f / C_SZ);
    lt *= (1.0f / C_SZ);
    out[1 + b]        = ls;
    out[1 + B_SZ + b] = lt;
    float v = 0.5f * ls + 0.5f * lt;
    #pragma unroll
    for (int o = 32; o > 0; o >>= 1) v += __shfl_down(v, o);
    if (b == 0) out[0] = v * (1.0f / B_SZ);
}

extern "C" void kernel_launch(void* const* d_in, const int* in_sizes, int n_in,
                              void* d_out, int out_size, void* d_ws, size_t ws_size,
                              hipStream_t stream) {
    const float* input  = (const float*)d_in[0];
    const float* target = (const float*)d_in[1];
    float* out = (float*)d_out;   // 129 floats

    float* sdtw = (float*)d_ws;                 // 512 floats
    float* wlt  = sdtw + BC_TOT;                // 512 floats

    dtw_fwd_kernel<<<BC_TOT, 64, 0, stream>>>(input, target, sdtw, wlt);
    finalize_kernel<<<1, 64, 0, stream>>>(sdtw, wlt, out);
}